// Round 1
// baseline (2985.178 us; speedup 1.0000x reference)
//
#include <hip/hip_runtime.h>
#include <cstdint>
#include <cstddef>

#define T_STEPS 64
#define F_INP 5
#define LOG2E 1.44269504088896340736f

typedef _Float16 f16x8 __attribute__((ext_vector_type(8)));
typedef float f32x4 __attribute__((ext_vector_type(4)));

__device__ __forceinline__ float leaky(float x, float s){ return x>0.f? x : s*x; }
__device__ __forceinline__ float rcpf(float x){ return __builtin_amdgcn_rcpf(x); }
__device__ __forceinline__ float exp2fast(float x){ return __builtin_amdgcn_exp2f(x); }

// ---------------- MFMA LSTM (fp16 single-product): 32 nodes/block, 4 waves.
// Wave wq owns gate-columns [16wq,16wq+16) of all 4 gates, m=0,1 node groups.
// i,f,o rows pre-scaled by log2e; g rows by 2*log2e. Activations:
//   cn = (c_old*(1+e_i)(1+e_g) + (e_g-1)(1+e_f)) / ((1+e_f)(1+e_i)(1+e_g))
//   hv = (e_c-1) / ((1+e_o)(1+e_c)),  e_c = exp2(2*log2e*cn)
// -> 5 exp + 2 rcp per cell element. t-loop unrolled x2 with separate LDS
// buffers so all ds addresses are loop-invariant.
// launch_bounds min-waves/EU raised 4 -> 8: VGPR=64 already fits 8 waves/SIMD,
// and measured occupancy (~40%) matched a 4-blocks/CU cap from waves-per-eu=4.
__global__ __launch_bounds__(256, 8) void lstm_mfma(
    const float* __restrict__ x, const float* __restrict__ W_ih,
    const float* __restrict__ W_hh, const float* __restrict__ b_ih,
    const float* __restrict__ b_hh, float* __restrict__ h_out, int N)
{
  __shared__ __align__(16) _Float16 Hs0[32][64];
  __shared__ __align__(16) _Float16 Hs1[32][64];
  __shared__ __align__(16) _Float16 Xs0[32][8];
  __shared__ __align__(16) _Float16 Xs1[32][8];
  __shared__ __align__(16) _Float16 Zero8[8];

  const int tid   = threadIdx.x;
  const int lane  = tid & 63;
  const int wq    = tid >> 6;      // 0..3 gate-col slice
  const int col16 = lane & 15;
  const int grp   = lane >> 4;
  const int base  = blockIdx.x * 32;

  // ---- B fragments (fp16). g gate (n==2) scaled 2*LOG2E; i,f,o by LOG2E.
  f16x8 Bh[4][2], Bx[4];
  #pragma unroll
  for (int n=0;n<4;n++){
    const float sc = (n==2) ? 2.f*LOG2E : LOG2E;
    const int gate = n*64 + wq*16 + col16;
    #pragma unroll
    for (int kk=0;kk<2;kk++){
      const float* p = W_hh + gate*64 + kk*32 + grp*8;
      #pragma unroll
      for (int e=0;e<8;e++) Bh[n][kk][e] = (_Float16)(p[e]*sc);
    }
    f16x8 bx = {0,0,0,0,0,0,0,0};
    if (grp==0){
      #pragma unroll
      for (int e=0;e<5;e++) bx[e] = (_Float16)(W_ih[gate*5+e]*sc);
      bx[5] = (_Float16)((b_ih[gate]+b_hh[gate])*sc);
    }
    Bx[n] = bx;
  }

  // zero Hs0 (4 KB = 256 float4) + Zero8
  ((float4*)&Hs0[0][0])[tid] = float4{0.f,0.f,0.f,0.f};
  if (tid==0) ((float4*)Zero8)[0] = float4{0.f,0.f,0.f,0.f};

  // x staging: threads 0..31 own node tid
  const int xnode = tid;               // valid when xown
  const bool xown = (tid < 32);
  const int gxn = base + xnode;
  if (xown){
    f16x8 xh = {0,0,0,0,0,0,0,0}; xh[5] = (_Float16)1.f;
    if (gxn < N){
      const float* xp_ = x + (size_t)gxn*(T_STEPS*F_INP);
      #pragma unroll
      for (int j=0;j<F_INP;j++) xh[j] = (_Float16)xp_[j];
    }
    *(f16x8*)&Xs0[xnode][0] = xh;
  }

  // loop-invariant LDS element offsets
  const int sw = (col16&7)<<3;
  int roff0[2], roff1[2], xoffm[2], soff[2][4];
  const int j = wq*16 + col16;
  #pragma unroll
  for (int m=0;m<2;m++){
    const int nodeA = 16*m + col16;
    roff0[m] = nodeA*64 + ((grp*8) ^ sw);
    roff1[m] = nodeA*64 + ((32 + grp*8) ^ sw);
    xoffm[m] = nodeA*8;
    #pragma unroll
    for (int r=0;r<4;r++){
      const int node = 16*m + 4*grp + r;
      soff[m][r] = node*64 + (j ^ ((4*(grp&1)+r)<<3));
    }
  }

  float creg[2][4];
  #pragma unroll
  for (int m=0;m<2;m++)
    #pragma unroll
    for (int r=0;r<4;r++) creg[m][r]=0.f;

  __syncthreads();

#define LSTM_STEP(HC, HN, XC, XN, T, LAST) {                                   \
    float xf0=0.f,xf1=0.f,xf2=0.f,xf3=0.f,xf4=0.f;                             \
    const bool xload = (!(LAST)) && xown && (gxn < N);                         \
    if (xload){                                                                \
      const float* xp_ = x + (size_t)gxn*(T_STEPS*F_INP) + ((T)+1)*F_INP;      \
      xf0=xp_[0];xf1=xp_[1];xf2=xp_[2];xf3=xp_[3];xf4=xp_[4];                  \
    }                                                                          \
    _Pragma("unroll")                                                          \
    for (int m=0;m<2;m++){                                                     \
      f16x8 a0 = *(const f16x8*)(&HC[0][0] + roff0[m]);                        \
      f16x8 a1 = *(const f16x8*)(&HC[0][0] + roff1[m]);                        \
      const _Float16* px = (grp==0) ? (&XC[0][0] + xoffm[m]) : Zero8;          \
      f16x8 ax = *(const f16x8*)px;                                            \
      f32x4 z4 = f32x4{0.f,0.f,0.f,0.f};                                       \
      f32x4 ac0=z4, ac1=z4, ac2=z4, ac3=z4;                                    \
      ac0 = __builtin_amdgcn_mfma_f32_16x16x32_f16(a0, Bh[0][0], ac0, 0,0,0);  \
      ac1 = __builtin_amdgcn_mfma_f32_16x16x32_f16(a0, Bh[1][0], ac1, 0,0,0);  \
      ac2 = __builtin_amdgcn_mfma_f32_16x16x32_f16(a0, Bh[2][0], ac2, 0,0,0);  \
      ac3 = __builtin_amdgcn_mfma_f32_16x16x32_f16(a0, Bh[3][0], ac3, 0,0,0);  \
      ac0 = __builtin_amdgcn_mfma_f32_16x16x32_f16(a1, Bh[0][1], ac0, 0,0,0);  \
      ac1 = __builtin_amdgcn_mfma_f32_16x16x32_f16(a1, Bh[1][1], ac1, 0,0,0);  \
      ac2 = __builtin_amdgcn_mfma_f32_16x16x32_f16(a1, Bh[2][1], ac2, 0,0,0);  \
      ac3 = __builtin_amdgcn_mfma_f32_16x16x32_f16(a1, Bh[3][1], ac3, 0,0,0);  \
      ac0 = __builtin_amdgcn_mfma_f32_16x16x32_f16(ax, Bx[0],    ac0, 0,0,0);  \
      ac1 = __builtin_amdgcn_mfma_f32_16x16x32_f16(ax, Bx[1],    ac1, 0,0,0);  \
      ac2 = __builtin_amdgcn_mfma_f32_16x16x32_f16(ax, Bx[2],    ac2, 0,0,0);  \
      ac3 = __builtin_amdgcn_mfma_f32_16x16x32_f16(ax, Bx[3],    ac3, 0,0,0);  \
      _Pragma("unroll")                                                        \
      for (int r=0;r<4;r++){                                                   \
        float e_i = exp2fast(-ac0[r]);                                         \
        float e_f = exp2fast(-ac1[r]);                                         \
        float zg2 = fminf(ac2[r], 60.f);                                       \
        float e_g = exp2fast(zg2);                                             \
        float e_o = exp2fast(-ac3[r]);                                         \
        float Ag = (1.f+e_i)*(1.f+e_g);                                        \
        float Bf = 1.f+e_f;                                                    \
        float rD = rcpf(Ag*Bf);                                                \
        float cn = (creg[m][r]*Ag + (e_g-1.f)*Bf)*rD;                          \
        creg[m][r] = cn;                                                       \
        float c2 = fminf(cn*(2.f*LOG2E), 120.f);                               \
        float e_c = exp2fast(c2);                                              \
        float hv = (e_c-1.f)*rcpf((1.f+e_o)*(1.f+e_c));                        \
        if (LAST){                                                             \
          const int gn = base + 16*m + 4*grp + r;                              \
          if (gn < N) h_out[(size_t)gn*64 + j] = hv;                           \
        } else {                                                               \
          (&HN[0][0])[soff[m][r]] = (_Float16)hv;                              \
        }                                                                      \
      }                                                                        \
    }                                                                          \
    if (!(LAST) && xown){                                                      \
      f16x8 xh = {0,0,0,0,0,0,0,0}; xh[5] = (_Float16)1.f;                     \
      if (xload){                                                              \
        xh[0]=(_Float16)xf0; xh[1]=(_Float16)xf1; xh[2]=(_Float16)xf2;         \
        xh[3]=(_Float16)xf3; xh[4]=(_Float16)xf4;                              \
      }                                                                        \
      *(f16x8*)&XN[xnode][0] = xh;                                             \
    }                                                                          \
  }

  for (int tt=0; tt<T_STEPS/2; ++tt){
    LSTM_STEP(Hs0, Hs1, Xs0, Xs1, 2*tt, false);
    __syncthreads();
    LSTM_STEP(Hs1, Hs0, Xs1, Xs0, 2*tt+1, (tt==T_STEPS/2-1));
    __syncthreads();
  }
#undef LSTM_STEP
}

// ---------------- GAT setup (one 64-thread block), wave-parallel:
// mode detect via ballot; vcomb = gat_w^T {att_src, att_dst, fc_w};
// bias-dot scalar via shfl reduce.
__global__ void gat_setup(const int* __restrict__ ei,
                          const float* __restrict__ gat_w,
                          const float* __restrict__ att_src,
                          const float* __restrict__ att_dst,
                          const float* __restrict__ fc_w,
                          const float* __restrict__ gat_bias,
                          const float* __restrict__ fc_b,
                          float* __restrict__ vcomb,
                          unsigned* __restrict__ mode)
{
  int j = threadIdx.x;   // 0..63, one full wave
  // mode: 1 iff first 64 int32 "high" slots are all zero (int64 edge_index)
  unsigned long long nz = __ballot(ei[2*j+1] != 0);
  float bdp = gat_bias[j]*fc_w[j];
  #pragma unroll
  for (int off=32; off; off>>=1) bdp += __shfl_down(bdp, off);
  if (j==0){
    *mode = (nz==0ULL) ? 1u : 0u;
    vcomb[192] = bdp + fc_b[0];
  }
  float va=0.f, vd=0.f, vf=0.f;
  #pragma unroll 8
  for (int k=0;k<64;k++){
    float g = gat_w[k*64+j];
    va += att_src[k]*g;
    vd += att_dst[k]*g;
    vf += fc_w[k]*g;
  }
  vcomb[j]=va; vcomb[64+j]=vd; vcomb[128+j]=vf;
}

// ---------------- GAT prep: 3 dot products per node against vcomb ----------
__global__ __launch_bounds__(256) void gat_prep(
    const float* __restrict__ h_in, const float* __restrict__ vcomb,
    float* __restrict__ a_src, float* __restrict__ a_dst,
    float* __restrict__ xfv, float* __restrict__ denom,
    float* __restrict__ oacc, int N)
{
  int n = blockIdx.x*256 + threadIdx.x;
  if (n>=N) return;
  const float4* hp = (const float4*)(h_in + (size_t)n*64);
  const float4* va = (const float4*)vcomb;
  const float4* vd = (const float4*)(vcomb+64);
  const float4* vf = (const float4*)(vcomb+128);
  float as=0.f, ad=0.f, xf=0.f;
  #pragma unroll
  for (int q=0;q<16;q++){
    float4 h = hp[q], a = va[q], d = vd[q], f = vf[q];
    as += a.x*h.x + a.y*h.y + a.z*h.z + a.w*h.w;
    ad += d.x*h.x + d.y*h.y + d.z*h.z + d.w*h.w;
    xf += f.x*h.x + f.y*h.y + f.z*h.z + f.w*h.w;
  }
  a_src[n]=as; a_dst[n]=ad; xfv[n]=xf;
  denom[n]=0.f; oacc[n]=0.f;
}

__device__ __forceinline__ void load_edge(const int* ei, unsigned mode,
                                          long long e, long long E,
                                          int& s, int& d)
{
  if (e>=E){ s=d=(int)(e-E); }
  else if (mode){
    const long long* e64 = (const long long*)ei;
    s=(int)e64[e]; d=(int)e64[E+e];
  } else {
    s=ei[e]; d=ei[E+e];
  }
}

// single pass: softmax normalization deferred to finalize.
// out[d] = (sum_e ew_e * xf_s) / (sum_e ew_e): divide once per node instead
// of once per edge -> no eww buffer, no second edge sweep.
__global__ __launch_bounds__(256) void edge_pass(
    const int* __restrict__ ei, const unsigned* __restrict__ mode_p,
    const float* __restrict__ a_src, const float* __restrict__ a_dst,
    const float* __restrict__ xfv,
    float* __restrict__ denom, float* __restrict__ oacc,
    long long E, long long total)
{
  long long e = (long long)blockIdx.x*256 + threadIdx.x;
  if (e>=total) return;
  int s,d;
  load_edge(ei, *mode_p, e, E, s, d);
  float al = leaky(a_src[s]+a_dst[d], 0.2f);
  float ew = __expf(al);
  atomicAdd(&denom[d], ew);
  atomicAdd(&oacc[d], ew * xfv[s]);
}

__global__ __launch_bounds__(256) void finalize(
    const float* __restrict__ oacc, const float* __restrict__ denom,
    const float* __restrict__ vcomb, float* __restrict__ out, int N)
{
  int n = blockIdx.x*256+threadIdx.x;
  if (n>=N) return;
  float v = oacc[n] * rcpf(denom[n]) + vcomb[192];
  out[n] = leaky(v, 0.01f);
}

extern "C" void kernel_launch(void* const* d_in, const int* in_sizes, int n_in,
                              void* d_out, int out_size, void* d_ws, size_t ws_size,
                              hipStream_t stream)
{
  const float* x      = (const float*)d_in[0];
  const float* W_ih   = (const float*)d_in[1];
  const float* W_hh   = (const float*)d_in[2];
  const float* b_ih   = (const float*)d_in[3];
  const float* b_hh   = (const float*)d_in[4];
  const float* gat_w  = (const float*)d_in[5];
  const float* att_s  = (const float*)d_in[6];
  const float* att_d  = (const float*)d_in[7];
  const float* gat_b  = (const float*)d_in[8];
  const float* fc_w   = (const float*)d_in[9];
  const float* fc_b   = (const float*)d_in[10];
  const int*   ei     = (const int*)d_in[11];

  const int N = in_sizes[0]/(T_STEPS*F_INP);
  const long long E = in_sizes[11]/2;
  const long long total = E + N;

  float* ws = (float*)d_ws;
  size_t off = 0;
  float* h_out   = ws + off; off += (size_t)N*64;
  float* a_src   = ws + off; off += (size_t)N;
  float* a_dst   = ws + off; off += (size_t)N;
  float* xfv     = ws + off; off += (size_t)N;
  float* denom   = ws + off; off += (size_t)N;
  float* oacc    = ws + off; off += (size_t)N;
  float* vcomb   = ws + off; off += 256;
  unsigned* mode = (unsigned*)(ws + off); off += 1;

  gat_setup<<<1,64,0,stream>>>(ei, gat_w, att_s, att_d, fc_w, gat_b, fc_b, vcomb, mode);

  lstm_mfma<<<dim3((N+31)/32), dim3(256), 0, stream>>>(
      x, W_ih, W_hh, b_ih, b_hh, h_out, N);

  gat_prep<<<dim3((N+255)/256), dim3(256), 0, stream>>>(
      h_out, vcomb, a_src, a_dst, xfv, denom, oacc, N);

  int eb = (int)((total+255)/256);
  edge_pass<<<dim3(eb), dim3(256), 0, stream>>>(ei, mode, a_src, a_dst, xfv, denom, oacc, E, total);

  finalize<<<dim3((N+255)/256), dim3(256), 0, stream>>>(oacc, denom, vcomb, (float*)d_out, N);
}

// Round 2
// 661.393 us; speedup vs baseline: 4.5135x; 4.5135x over previous
//
#include <hip/hip_runtime.h>
#include <cstdint>
#include <cstddef>

#define T_STEPS 64
#define F_INP 5
#define LOG2E 1.44269504088896340736f

typedef _Float16 f16x8 __attribute__((ext_vector_type(8)));
typedef float f32x4 __attribute__((ext_vector_type(4)));

__device__ __forceinline__ float leaky(float x, float s){ return x>0.f? x : s*x; }
__device__ __forceinline__ float rcpf(float x){ return __builtin_amdgcn_rcpf(x); }
__device__ __forceinline__ float exp2fast(float x){ return __builtin_amdgcn_exp2f(x); }

// ---------------- MFMA LSTM (fp16 single-product): 32 nodes/block, 4 waves.
// Wave wq owns gate-columns [16wq,16wq+16) of all 4 gates, m=0,1 node groups.
// i,f,o rows pre-scaled by log2e; g rows by 2*log2e. Activations:
//   cn = (c_old*(1+e_i)(1+e_g) + (e_g-1)(1+e_f)) / ((1+e_f)(1+e_i)(1+e_g))
//   hv = (e_c-1) / ((1+e_o)(1+e_c)),  e_c = exp2(2*log2e*cn)
// -> 5 exp + 2 rcp per cell element. t-loop unrolled x2 with separate LDS
// buffers so all ds addresses are loop-invariant.
// NOTE: __launch_bounds__ second arg MUST stay 4. Raising it to 8 caps the
// unified VGPR budget at 64 total -> allocator drops to 32 arch VGPRs and
// spills the B-fragments: measured FETCH_SIZE 64MB -> 8.9GB, dur 562 -> 2844us.
__global__ __launch_bounds__(256, 4) void lstm_mfma(
    const float* __restrict__ x, const float* __restrict__ W_ih,
    const float* __restrict__ W_hh, const float* __restrict__ b_ih,
    const float* __restrict__ b_hh, float* __restrict__ h_out, int N)
{
  __shared__ __align__(16) _Float16 Hs0[32][64];
  __shared__ __align__(16) _Float16 Hs1[32][64];
  __shared__ __align__(16) _Float16 Xs0[32][8];
  __shared__ __align__(16) _Float16 Xs1[32][8];
  __shared__ __align__(16) _Float16 Zero8[8];

  const int tid   = threadIdx.x;
  const int lane  = tid & 63;
  const int wq    = tid >> 6;      // 0..3 gate-col slice
  const int col16 = lane & 15;
  const int grp   = lane >> 4;
  const int base  = blockIdx.x * 32;

  // ---- B fragments (fp16). g gate (n==2) scaled 2*LOG2E; i,f,o by LOG2E.
  f16x8 Bh[4][2], Bx[4];
  #pragma unroll
  for (int n=0;n<4;n++){
    const float sc = (n==2) ? 2.f*LOG2E : LOG2E;
    const int gate = n*64 + wq*16 + col16;
    #pragma unroll
    for (int kk=0;kk<2;kk++){
      const float* p = W_hh + gate*64 + kk*32 + grp*8;
      #pragma unroll
      for (int e=0;e<8;e++) Bh[n][kk][e] = (_Float16)(p[e]*sc);
    }
    f16x8 bx = {0,0,0,0,0,0,0,0};
    if (grp==0){
      #pragma unroll
      for (int e=0;e<5;e++) bx[e] = (_Float16)(W_ih[gate*5+e]*sc);
      bx[5] = (_Float16)((b_ih[gate]+b_hh[gate])*sc);
    }
    Bx[n] = bx;
  }

  // zero Hs0 (4 KB = 256 float4) + Zero8
  ((float4*)&Hs0[0][0])[tid] = float4{0.f,0.f,0.f,0.f};
  if (tid==0) ((float4*)Zero8)[0] = float4{0.f,0.f,0.f,0.f};

  // x staging: threads 0..31 own node tid
  const int xnode = tid;               // valid when xown
  const bool xown = (tid < 32);
  const int gxn = base + xnode;
  if (xown){
    f16x8 xh = {0,0,0,0,0,0,0,0}; xh[5] = (_Float16)1.f;
    if (gxn < N){
      const float* xp_ = x + (size_t)gxn*(T_STEPS*F_INP);
      #pragma unroll
      for (int j=0;j<F_INP;j++) xh[j] = (_Float16)xp_[j];
    }
    *(f16x8*)&Xs0[xnode][0] = xh;
  }

  // loop-invariant LDS element offsets
  const int sw = (col16&7)<<3;
  int roff0[2], roff1[2], xoffm[2], soff[2][4];
  const int j = wq*16 + col16;
  #pragma unroll
  for (int m=0;m<2;m++){
    const int nodeA = 16*m + col16;
    roff0[m] = nodeA*64 + ((grp*8) ^ sw);
    roff1[m] = nodeA*64 + ((32 + grp*8) ^ sw);
    xoffm[m] = nodeA*8;
    #pragma unroll
    for (int r=0;r<4;r++){
      const int node = 16*m + 4*grp + r;
      soff[m][r] = node*64 + (j ^ ((4*(grp&1)+r)<<3));
    }
  }

  float creg[2][4];
  #pragma unroll
  for (int m=0;m<2;m++)
    #pragma unroll
    for (int r=0;r<4;r++) creg[m][r]=0.f;

  __syncthreads();

#define LSTM_STEP(HC, HN, XC, XN, T, LAST) {                                   \
    float xf0=0.f,xf1=0.f,xf2=0.f,xf3=0.f,xf4=0.f;                             \
    const bool xload = (!(LAST)) && xown && (gxn < N);                         \
    if (xload){                                                                \
      const float* xp_ = x + (size_t)gxn*(T_STEPS*F_INP) + ((T)+1)*F_INP;      \
      xf0=xp_[0];xf1=xp_[1];xf2=xp_[2];xf3=xp_[3];xf4=xp_[4];                  \
    }                                                                          \
    _Pragma("unroll")                                                          \
    for (int m=0;m<2;m++){                                                     \
      f16x8 a0 = *(const f16x8*)(&HC[0][0] + roff0[m]);                        \
      f16x8 a1 = *(const f16x8*)(&HC[0][0] + roff1[m]);                        \
      const _Float16* px = (grp==0) ? (&XC[0][0] + xoffm[m]) : Zero8;          \
      f16x8 ax = *(const f16x8*)px;                                            \
      f32x4 z4 = f32x4{0.f,0.f,0.f,0.f};                                       \
      f32x4 ac0=z4, ac1=z4, ac2=z4, ac3=z4;                                    \
      ac0 = __builtin_amdgcn_mfma_f32_16x16x32_f16(a0, Bh[0][0], ac0, 0,0,0);  \
      ac1 = __builtin_amdgcn_mfma_f32_16x16x32_f16(a0, Bh[1][0], ac1, 0,0,0);  \
      ac2 = __builtin_amdgcn_mfma_f32_16x16x32_f16(a0, Bh[2][0], ac2, 0,0,0);  \
      ac3 = __builtin_amdgcn_mfma_f32_16x16x32_f16(a0, Bh[3][0], ac3, 0,0,0);  \
      ac0 = __builtin_amdgcn_mfma_f32_16x16x32_f16(a1, Bh[0][1], ac0, 0,0,0);  \
      ac1 = __builtin_amdgcn_mfma_f32_16x16x32_f16(a1, Bh[1][1], ac1, 0,0,0);  \
      ac2 = __builtin_amdgcn_mfma_f32_16x16x32_f16(a1, Bh[2][1], ac2, 0,0,0);  \
      ac3 = __builtin_amdgcn_mfma_f32_16x16x32_f16(a1, Bh[3][1], ac3, 0,0,0);  \
      ac0 = __builtin_amdgcn_mfma_f32_16x16x32_f16(ax, Bx[0],    ac0, 0,0,0);  \
      ac1 = __builtin_amdgcn_mfma_f32_16x16x32_f16(ax, Bx[1],    ac1, 0,0,0);  \
      ac2 = __builtin_amdgcn_mfma_f32_16x16x32_f16(ax, Bx[2],    ac2, 0,0,0);  \
      ac3 = __builtin_amdgcn_mfma_f32_16x16x32_f16(ax, Bx[3],    ac3, 0,0,0);  \
      _Pragma("unroll")                                                        \
      for (int r=0;r<4;r++){                                                   \
        float e_i = exp2fast(-ac0[r]);                                         \
        float e_f = exp2fast(-ac1[r]);                                         \
        float zg2 = fminf(ac2[r], 60.f);                                       \
        float e_g = exp2fast(zg2);                                             \
        float e_o = exp2fast(-ac3[r]);                                         \
        float Ag = (1.f+e_i)*(1.f+e_g);                                        \
        float Bf = 1.f+e_f;                                                    \
        float rD = rcpf(Ag*Bf);                                                \
        float cn = (creg[m][r]*Ag + (e_g-1.f)*Bf)*rD;                          \
        creg[m][r] = cn;                                                       \
        float c2 = fminf(cn*(2.f*LOG2E), 120.f);                               \
        float e_c = exp2fast(c2);                                              \
        float hv = (e_c-1.f)*rcpf((1.f+e_o)*(1.f+e_c));                        \
        if (LAST){                                                             \
          const int gn = base + 16*m + 4*grp + r;                              \
          if (gn < N) h_out[(size_t)gn*64 + j] = hv;                           \
        } else {                                                               \
          (&HN[0][0])[soff[m][r]] = (_Float16)hv;                              \
        }                                                                      \
      }                                                                        \
    }                                                                          \
    if (!(LAST) && xown){                                                      \
      f16x8 xh = {0,0,0,0,0,0,0,0}; xh[5] = (_Float16)1.f;                     \
      if (xload){                                                              \
        xh[0]=(_Float16)xf0; xh[1]=(_Float16)xf1; xh[2]=(_Float16)xf2;         \
        xh[3]=(_Float16)xf3; xh[4]=(_Float16)xf4;                              \
      }                                                                        \
      *(f16x8*)&XN[xnode][0] = xh;                                             \
    }                                                                          \
  }

  for (int tt=0; tt<T_STEPS/2; ++tt){
    LSTM_STEP(Hs0, Hs1, Xs0, Xs1, 2*tt, false);
    __syncthreads();
    LSTM_STEP(Hs1, Hs0, Xs1, Xs0, 2*tt+1, (tt==T_STEPS/2-1));
    __syncthreads();
  }
#undef LSTM_STEP
}

// ---------------- GAT setup (one 64-thread block), wave-parallel:
// mode detect via ballot; vcomb = gat_w^T {att_src, att_dst, fc_w};
// bias-dot scalar via shfl reduce.
__global__ void gat_setup(const int* __restrict__ ei,
                          const float* __restrict__ gat_w,
                          const float* __restrict__ att_src,
                          const float* __restrict__ att_dst,
                          const float* __restrict__ fc_w,
                          const float* __restrict__ gat_bias,
                          const float* __restrict__ fc_b,
                          float* __restrict__ vcomb,
                          unsigned* __restrict__ mode)
{
  int j = threadIdx.x;   // 0..63, one full wave
  // mode: 1 iff first 64 int32 "high" slots are all zero (int64 edge_index)
  unsigned long long nz = __ballot(ei[2*j+1] != 0);
  float bdp = gat_bias[j]*fc_w[j];
  #pragma unroll
  for (int off=32; off; off>>=1) bdp += __shfl_down(bdp, off);
  if (j==0){
    *mode = (nz==0ULL) ? 1u : 0u;
    vcomb[192] = bdp + fc_b[0];
  }
  float va=0.f, vd=0.f, vf=0.f;
  #pragma unroll 8
  for (int k=0;k<64;k++){
    float g = gat_w[k*64+j];
    va += att_src[k]*g;
    vd += att_dst[k]*g;
    vf += fc_w[k]*g;
  }
  vcomb[j]=va; vcomb[64+j]=vd; vcomb[128+j]=vf;
}

// ---------------- GAT prep: 3 dot products per node against vcomb ----------
__global__ __launch_bounds__(256) void gat_prep(
    const float* __restrict__ h_in, const float* __restrict__ vcomb,
    float* __restrict__ a_src, float* __restrict__ a_dst,
    float* __restrict__ xfv, float* __restrict__ denom,
    float* __restrict__ oacc, int N)
{
  int n = blockIdx.x*256 + threadIdx.x;
  if (n>=N) return;
  const float4* hp = (const float4*)(h_in + (size_t)n*64);
  const float4* va = (const float4*)vcomb;
  const float4* vd = (const float4*)(vcomb+64);
  const float4* vf = (const float4*)(vcomb+128);
  float as=0.f, ad=0.f, xf=0.f;
  #pragma unroll
  for (int q=0;q<16;q++){
    float4 h = hp[q], a = va[q], d = vd[q], f = vf[q];
    as += a.x*h.x + a.y*h.y + a.z*h.z + a.w*h.w;
    ad += d.x*h.x + d.y*h.y + d.z*h.z + d.w*h.w;
    xf += f.x*h.x + f.y*h.y + f.z*h.z + f.w*h.w;
  }
  a_src[n]=as; a_dst[n]=ad; xfv[n]=xf;
  denom[n]=0.f; oacc[n]=0.f;
}

__device__ __forceinline__ void load_edge(const int* ei, unsigned mode,
                                          long long e, long long E,
                                          int& s, int& d)
{
  if (e>=E){ s=d=(int)(e-E); }
  else if (mode){
    const long long* e64 = (const long long*)ei;
    s=(int)e64[e]; d=(int)e64[E+e];
  } else {
    s=ei[e]; d=ei[E+e];
  }
}

// single pass: softmax normalization deferred to finalize.
// out[d] = (sum_e ew_e * xf_s) / (sum_e ew_e): divide once per node instead
// of once per edge -> no eww buffer, no second edge sweep.
__global__ __launch_bounds__(256) void edge_pass(
    const int* __restrict__ ei, const unsigned* __restrict__ mode_p,
    const float* __restrict__ a_src, const float* __restrict__ a_dst,
    const float* __restrict__ xfv,
    float* __restrict__ denom, float* __restrict__ oacc,
    long long E, long long total)
{
  long long e = (long long)blockIdx.x*256 + threadIdx.x;
  if (e>=total) return;
  int s,d;
  load_edge(ei, *mode_p, e, E, s, d);
  float al = leaky(a_src[s]+a_dst[d], 0.2f);
  float ew = __expf(al);
  atomicAdd(&denom[d], ew);
  atomicAdd(&oacc[d], ew * xfv[s]);
}

__global__ __launch_bounds__(256) void finalize(
    const float* __restrict__ oacc, const float* __restrict__ denom,
    const float* __restrict__ vcomb, float* __restrict__ out, int N)
{
  int n = blockIdx.x*256+threadIdx.x;
  if (n>=N) return;
  float v = oacc[n] * rcpf(denom[n]) + vcomb[192];
  out[n] = leaky(v, 0.01f);
}

extern "C" void kernel_launch(void* const* d_in, const int* in_sizes, int n_in,
                              void* d_out, int out_size, void* d_ws, size_t ws_size,
                              hipStream_t stream)
{
  const float* x      = (const float*)d_in[0];
  const float* W_ih   = (const float*)d_in[1];
  const float* W_hh   = (const float*)d_in[2];
  const float* b_ih   = (const float*)d_in[3];
  const float* b_hh   = (const float*)d_in[4];
  const float* gat_w  = (const float*)d_in[5];
  const float* att_s  = (const float*)d_in[6];
  const float* att_d  = (const float*)d_in[7];
  const float* gat_b  = (const float*)d_in[8];
  const float* fc_w   = (const float*)d_in[9];
  const float* fc_b   = (const float*)d_in[10];
  const int*   ei     = (const int*)d_in[11];

  const int N = in_sizes[0]/(T_STEPS*F_INP);
  const long long E = in_sizes[11]/2;
  const long long total = E + N;

  float* ws = (float*)d_ws;
  size_t off = 0;
  float* h_out   = ws + off; off += (size_t)N*64;
  float* a_src   = ws + off; off += (size_t)N;
  float* a_dst   = ws + off; off += (size_t)N;
  float* xfv     = ws + off; off += (size_t)N;
  float* denom   = ws + off; off += (size_t)N;
  float* oacc    = ws + off; off += (size_t)N;
  float* vcomb   = ws + off; off += 256;
  unsigned* mode = (unsigned*)(ws + off); off += 1;

  gat_setup<<<1,64,0,stream>>>(ei, gat_w, att_s, att_d, fc_w, gat_b, fc_b, vcomb, mode);

  lstm_mfma<<<dim3((N+31)/32), dim3(256), 0, stream>>>(
      x, W_ih, W_hh, b_ih, b_hh, h_out, N);

  gat_prep<<<dim3((N+255)/256), dim3(256), 0, stream>>>(
      h_out, vcomb, a_src, a_dst, xfv, denom, oacc, N);

  int eb = (int)((total+255)/256);
  edge_pass<<<dim3(eb), dim3(256), 0, stream>>>(ei, mode, a_src, a_dst, xfv, denom, oacc, E, total);

  finalize<<<dim3((N+255)/256), dim3(256), 0, stream>>>(oacc, denom, vcomb, (float*)d_out, N);
}

// Round 3
// 650.616 us; speedup vs baseline: 4.5882x; 1.0166x over previous
//
#include <hip/hip_runtime.h>
#include <cstdint>
#include <cstddef>

#define T_STEPS 64
#define F_INP 5
#define LOG2E 1.44269504088896340736f

typedef _Float16 f16x8 __attribute__((ext_vector_type(8)));
typedef float f32x4 __attribute__((ext_vector_type(4)));

__device__ __forceinline__ float leaky(float x, float s){ return x>0.f? x : s*x; }
__device__ __forceinline__ float rcpf(float x){ return __builtin_amdgcn_rcpf(x); }
__device__ __forceinline__ float exp2fast(float x){ return __builtin_amdgcn_exp2f(x); }

// ---------------- MFMA LSTM + fused GAT-prep epilogue.
// 32 nodes/block, 4 waves. Wave wq owns gate-columns [16wq,16wq+16) of all 4
// gates. Trans-op floor: 5 exp + 2 rcp per cell element (algebraic minimum).
// Round-3 changes vs 562us baseline:
//  1. x staging distributed over 160 threads (was: wave 0 only -> barrier
//     straggler); constant Xs[.][5..7] written once before the loop.
//  2. Both m-groups' 24 MFMAs issued before any activation math: m1's MFMA
//     issue covers m0's matrix-pipe drain (was: act(m0) stalled on it).
//  3. Final h kept in LDS (f32), epilogue computes a_src/a_dst/xfv dots
//     in-block -> h never written to HBM, gat_prep kernel deleted.
// NOTE: __launch_bounds__ second arg MUST stay 4. Raising to 8 caps unified
// VGPR budget at 64 -> B-fragments spill: FETCH 64MB -> 8.9GB, 562 -> 2844us.
__global__ __launch_bounds__(256, 4) void lstm_mfma(
    const float* __restrict__ x, const float* __restrict__ W_ih,
    const float* __restrict__ W_hh, const float* __restrict__ b_ih,
    const float* __restrict__ b_hh, const float* __restrict__ vcomb,
    float2* __restrict__ asx, float* __restrict__ a_dst,
    float* __restrict__ denom, float* __restrict__ oacc, int N)
{
  __shared__ __align__(16) _Float16 Hs0[32][64];
  __shared__ __align__(16) _Float16 Hs1[32][64];
  __shared__ __align__(16) _Float16 Xs0[32][8];
  __shared__ __align__(16) _Float16 Xs1[32][8];
  __shared__ __align__(16) _Float16 Zero8[8];
  __shared__ __align__(16) float    Hf[32][65];   // f32 final h (pad 65)

  const int tid   = threadIdx.x;
  const int lane  = tid & 63;
  const int wq    = tid >> 6;      // 0..3 gate-col slice
  const int col16 = lane & 15;
  const int grp   = lane >> 4;
  const int base  = blockIdx.x * 32;

  // ---- B fragments (fp16). g gate (n==2) scaled 2*LOG2E; i,f,o by LOG2E.
  f16x8 Bh[4][2], Bx[4];
  #pragma unroll
  for (int n=0;n<4;n++){
    const float sc = (n==2) ? 2.f*LOG2E : LOG2E;
    const int gate = n*64 + wq*16 + col16;
    #pragma unroll
    for (int kk=0;kk<2;kk++){
      const float* p = W_hh + gate*64 + kk*32 + grp*8;
      #pragma unroll
      for (int e=0;e<8;e++) Bh[n][kk][e] = (_Float16)(p[e]*sc);
    }
    f16x8 bx = {0,0,0,0,0,0,0,0};
    if (grp==0){
      #pragma unroll
      for (int e=0;e<5;e++) bx[e] = (_Float16)(W_ih[gate*5+e]*sc);
      bx[5] = (_Float16)((b_ih[gate]+b_hh[gate])*sc);
    }
    Bx[n] = bx;
  }

  // zero Hs0 (4 KB = 256 float4) + Zero8
  ((float4*)&Hs0[0][0])[tid] = float4{0.f,0.f,0.f,0.f};
  if (tid==0) ((float4*)Zero8)[0] = float4{0.f,0.f,0.f,0.f};

  // ---- distributed x staging: thread tid<160 owns (node=tid/5, elem=tid%5)
  const int  xn5  = tid/5, xe5 = tid - xn5*5;
  const bool xact = (tid < 160);
  const int  gxnode = base + xn5;
  const bool xlive  = xact && (gxnode < N);
  // running pointer: at tt-iteration start points to x[node][2tt+1][xe5]
  const float* xptr = x + (size_t)(xlive ? gxnode : 0)*(T_STEPS*F_INP) + xe5 + F_INP;
  if (xact){
    float v0 = xlive ? x[(size_t)gxnode*(T_STEPS*F_INP) + xe5] : 0.f;
    Xs0[xn5][xe5] = (_Float16)v0;
  }
  if (tid < 32){
    Xs0[tid][5]=(_Float16)1.f; Xs0[tid][6]=(_Float16)0.f; Xs0[tid][7]=(_Float16)0.f;
    Xs1[tid][5]=(_Float16)1.f; Xs1[tid][6]=(_Float16)0.f; Xs1[tid][7]=(_Float16)0.f;
  }

  // loop-invariant LDS element offsets
  const int sw = (col16&7)<<3;
  int roff0[2], roff1[2], xoffm[2], soff[2][4];
  const int j = wq*16 + col16;
  #pragma unroll
  for (int m=0;m<2;m++){
    const int nodeA = 16*m + col16;
    roff0[m] = nodeA*64 + ((grp*8) ^ sw);
    roff1[m] = nodeA*64 + ((32 + grp*8) ^ sw);
    xoffm[m] = nodeA*8;
    #pragma unroll
    for (int r=0;r<4;r++){
      const int node = 16*m + 4*grp + r;
      soff[m][r] = node*64 + (j ^ ((4*(grp&1)+r)<<3));
    }
  }

  float creg[2][4];
  #pragma unroll
  for (int m=0;m<2;m++)
    #pragma unroll
    for (int r=0;r<4;r++) creg[m][r]=0.f;

  __syncthreads();

// XOFF: byte-free element offset from xptr for the NEXT timestep's x.
#define LSTM_STEP(HC, HN, XC, XN, XOFF, LAST) {                                \
    float xval = 0.f;                                                          \
    if (!(LAST) && xlive) xval = xptr[XOFF];                                   \
    f32x4 AC0[2], AC1[2], AC2[2], AC3[2];                                      \
    _Pragma("unroll")                                                          \
    for (int m=0;m<2;m++){                                                     \
      f16x8 a0 = *(const f16x8*)(&HC[0][0] + roff0[m]);                        \
      f16x8 a1 = *(const f16x8*)(&HC[0][0] + roff1[m]);                        \
      const _Float16* px = (grp==0) ? (&XC[0][0] + xoffm[m]) : Zero8;          \
      f16x8 ax = *(const f16x8*)px;                                            \
      f32x4 z4 = f32x4{0.f,0.f,0.f,0.f};                                       \
      f32x4 c0=z4, c1=z4, c2=z4, c3=z4;                                        \
      c0 = __builtin_amdgcn_mfma_f32_16x16x32_f16(a0, Bh[0][0], c0, 0,0,0);    \
      c1 = __builtin_amdgcn_mfma_f32_16x16x32_f16(a0, Bh[1][0], c1, 0,0,0);    \
      c2 = __builtin_amdgcn_mfma_f32_16x16x32_f16(a0, Bh[2][0], c2, 0,0,0);    \
      c3 = __builtin_amdgcn_mfma_f32_16x16x32_f16(a0, Bh[3][0], c3, 0,0,0);    \
      c0 = __builtin_amdgcn_mfma_f32_16x16x32_f16(a1, Bh[0][1], c0, 0,0,0);    \
      c1 = __builtin_amdgcn_mfma_f32_16x16x32_f16(a1, Bh[1][1], c1, 0,0,0);    \
      c2 = __builtin_amdgcn_mfma_f32_16x16x32_f16(a1, Bh[2][1], c2, 0,0,0);    \
      c3 = __builtin_amdgcn_mfma_f32_16x16x32_f16(a1, Bh[3][1], c3, 0,0,0);    \
      c0 = __builtin_amdgcn_mfma_f32_16x16x32_f16(ax, Bx[0],    c0, 0,0,0);    \
      c1 = __builtin_amdgcn_mfma_f32_16x16x32_f16(ax, Bx[1],    c1, 0,0,0);    \
      c2 = __builtin_amdgcn_mfma_f32_16x16x32_f16(ax, Bx[2],    c2, 0,0,0);    \
      c3 = __builtin_amdgcn_mfma_f32_16x16x32_f16(ax, Bx[3],    c3, 0,0,0);    \
      AC0[m]=c0; AC1[m]=c1; AC2[m]=c2; AC3[m]=c3;                              \
    }                                                                          \
    _Pragma("unroll")                                                          \
    for (int m=0;m<2;m++){                                                     \
      _Pragma("unroll")                                                        \
      for (int r=0;r<4;r++){                                                   \
        float e_i = exp2fast(-AC0[m][r]);                                      \
        float e_f = exp2fast(-AC1[m][r]);                                      \
        float zg2 = fminf(AC2[m][r], 60.f);                                    \
        float e_g = exp2fast(zg2);                                             \
        float e_o = exp2fast(-AC3[m][r]);                                      \
        float Ag = (1.f+e_i)*(1.f+e_g);                                        \
        float Bf = 1.f+e_f;                                                    \
        float rD = rcpf(Ag*Bf);                                                \
        float cn = (creg[m][r]*Ag + (e_g-1.f)*Bf)*rD;                          \
        creg[m][r] = cn;                                                       \
        float c2v = fminf(cn*(2.f*LOG2E), 120.f);                              \
        float e_c = exp2fast(c2v);                                             \
        float hv = (e_c-1.f)*rcpf((1.f+e_o)*(1.f+e_c));                        \
        if (LAST){                                                             \
          Hf[16*m+4*grp+r][j] = hv;                                            \
        } else {                                                               \
          (&HN[0][0])[soff[m][r]] = (_Float16)hv;                              \
        }                                                                      \
      }                                                                        \
    }                                                                          \
    if (!(LAST) && xact) XN[xn5][xe5] = (_Float16)xval;                        \
  }

  for (int tt=0; tt<T_STEPS/2; ++tt){
    LSTM_STEP(Hs0, Hs1, Xs0, Xs1, 0, false);
    __syncthreads();
    LSTM_STEP(Hs1, Hs0, Xs1, Xs0, F_INP, (tt==T_STEPS/2-1));
    __syncthreads();
    xptr += 2*F_INP;
  }
#undef LSTM_STEP

  // ---- fused GAT prep: 8 threads per node, dot h (f32, LDS) with vcomb.
  const int en = tid >> 3, es = tid & 7;
  const int gn2 = base + en;
  float as=0.f, ad=0.f, xf=0.f;
  #pragma unroll
  for (int q=0;q<8;q++){
    float hv = Hf[en][es*8+q];
    as = fmaf(hv, vcomb[es*8+q],     as);
    ad = fmaf(hv, vcomb[64+es*8+q],  ad);
    xf = fmaf(hv, vcomb[128+es*8+q], xf);
  }
  #pragma unroll
  for (int off=1; off<8; off<<=1){
    as += __shfl_xor(as, off);
    ad += __shfl_xor(ad, off);
    xf += __shfl_xor(xf, off);
  }
  if (es==0 && gn2 < N){
    asx[gn2]   = float2{as, xf};
    a_dst[gn2] = ad;
    denom[gn2] = 0.f;
    oacc[gn2]  = 0.f;
  }
}

// ---------------- GAT setup (one 64-thread block), wave-parallel:
// mode detect via ballot; vcomb = gat_w^T {att_src, att_dst, fc_w};
// bias-dot scalar via shfl reduce.
__global__ void gat_setup(const int* __restrict__ ei,
                          const float* __restrict__ gat_w,
                          const float* __restrict__ att_src,
                          const float* __restrict__ att_dst,
                          const float* __restrict__ fc_w,
                          const float* __restrict__ gat_bias,
                          const float* __restrict__ fc_b,
                          float* __restrict__ vcomb,
                          unsigned* __restrict__ mode)
{
  int j = threadIdx.x;   // 0..63, one full wave
  // mode: 1 iff first 64 int32 "high" slots are all zero (int64 edge_index)
  unsigned long long nz = __ballot(ei[2*j+1] != 0);
  float bdp = gat_bias[j]*fc_w[j];
  #pragma unroll
  for (int off=32; off; off>>=1) bdp += __shfl_down(bdp, off);
  if (j==0){
    *mode = (nz==0ULL) ? 1u : 0u;
    vcomb[192] = bdp + fc_b[0];
  }
  float va=0.f, vd=0.f, vf=0.f;
  #pragma unroll 8
  for (int k=0;k<64;k++){
    float g = gat_w[k*64+j];
    va += att_src[k]*g;
    vd += att_dst[k]*g;
    vf += fc_w[k]*g;
  }
  vcomb[j]=va; vcomb[64+j]=vd; vcomb[128+j]=vf;
}

__device__ __forceinline__ void load_edge(const int* ei, unsigned mode,
                                          long long e, long long E,
                                          int& s, int& d)
{
  if (e>=E){ s=d=(int)(e-E); }
  else if (mode){
    const long long* e64 = (const long long*)ei;
    s=(int)e64[e]; d=(int)e64[E+e];
  } else {
    s=ei[e]; d=ei[E+e];
  }
}

// single pass: softmax normalization deferred to finalize.
// out[d] = (sum ew*xf_s)/(sum ew). asx packs {a_src, xfv} -> one 8B gather.
__global__ __launch_bounds__(256) void edge_pass(
    const int* __restrict__ ei, const unsigned* __restrict__ mode_p,
    const float2* __restrict__ asx, const float* __restrict__ a_dst,
    float* __restrict__ denom, float* __restrict__ oacc,
    long long E, long long total)
{
  long long e = (long long)blockIdx.x*256 + threadIdx.x;
  if (e>=total) return;
  int s,d;
  load_edge(ei, *mode_p, e, E, s, d);
  float2 sv = asx[s];
  float al = leaky(sv.x + a_dst[d], 0.2f);
  float ew = __expf(al);
  atomicAdd(&denom[d], ew);
  atomicAdd(&oacc[d], ew * sv.y);
}

__global__ __launch_bounds__(256) void finalize(
    const float* __restrict__ oacc, const float* __restrict__ denom,
    const float* __restrict__ vcomb, float* __restrict__ out, int N)
{
  int n = blockIdx.x*256+threadIdx.x;
  if (n>=N) return;
  float v = oacc[n] * rcpf(denom[n]) + vcomb[192];
  out[n] = leaky(v, 0.01f);
}

extern "C" void kernel_launch(void* const* d_in, const int* in_sizes, int n_in,
                              void* d_out, int out_size, void* d_ws, size_t ws_size,
                              hipStream_t stream)
{
  const float* x      = (const float*)d_in[0];
  const float* W_ih   = (const float*)d_in[1];
  const float* W_hh   = (const float*)d_in[2];
  const float* b_ih   = (const float*)d_in[3];
  const float* b_hh   = (const float*)d_in[4];
  const float* gat_w  = (const float*)d_in[5];
  const float* att_s  = (const float*)d_in[6];
  const float* att_d  = (const float*)d_in[7];
  const float* gat_b  = (const float*)d_in[8];
  const float* fc_w   = (const float*)d_in[9];
  const float* fc_b   = (const float*)d_in[10];
  const int*   ei     = (const int*)d_in[11];

  const int N = in_sizes[0]/(T_STEPS*F_INP);
  const long long E = in_sizes[11]/2;
  const long long total = E + N;

  float* ws = (float*)d_ws;
  size_t off = 0;
  float2* asx    = (float2*)(ws + off); off += (size_t)2*N;
  float* a_dst   = ws + off; off += (size_t)N;
  float* denom   = ws + off; off += (size_t)N;
  float* oacc    = ws + off; off += (size_t)N;
  float* vcomb   = ws + off; off += 256;
  unsigned* mode = (unsigned*)(ws + off); off += 1;

  gat_setup<<<1,64,0,stream>>>(ei, gat_w, att_s, att_d, fc_w, gat_b, fc_b, vcomb, mode);

  lstm_mfma<<<dim3((N+31)/32), dim3(256), 0, stream>>>(
      x, W_ih, W_hh, b_ih, b_hh, vcomb, asx, a_dst, denom, oacc, N);

  int eb = (int)((total+255)/256);
  edge_pass<<<dim3(eb), dim3(256), 0, stream>>>(ei, mode, asx, a_dst, denom, oacc, E, total);

  finalize<<<dim3((N+255)/256), dim3(256), 0, stream>>>(oacc, denom, vcomb, (float*)d_out, N);
}